// Round 1
// baseline (100.439 us; speedup 1.0000x reference)
//
#include <hip/hip_runtime.h>
#include <hip/hip_bf16.h>

// InnerProductFeatures: V=131072, C=64, D=8
//   xr[v,d,c] = x[v, d*64 + c]
//   s[v,k]    = sum_{d,c} xr[v,d,c] * W[c,k,d]          (W flat: c*64 + k*8 + d)
//   xOx[v,i]  = sum_k s[v,k] * xr[v,k,i]
//   out       = tanh(xOx)    shape (V, 64) fp32
//
// One wave (64 lanes) per row. Lane l: d0 = l>>4, c0 = (l&15)*4.
// Holds float4 a = xr[v, d0, c0..c0+3]   = x4[v*128 + l]
//       float4 b = xr[v, d0+4, c0..c0+3] = x4[v*128 + 64 + l]
// -> two fully-contiguous 1KiB wave loads per row.

__device__ __forceinline__ float fast_tanh(float x) {
    // 1 - 2/(e^{2x}+1); saturates to +/-1 correctly for large |x|
    float e = __expf(2.0f * x);
    return 1.0f - 2.0f / (e + 1.0f);
}

__global__ __launch_bounds__(256, 4)
void ipf_kernel(const float* __restrict__ x, const float* __restrict__ W,
                float* __restrict__ out, int V) {
    const int tid   = blockIdx.x * blockDim.x + threadIdx.x;
    const int lane  = threadIdx.x & 63;
    const int wave  = tid >> 6;
    const int nwav  = (gridDim.x * blockDim.x) >> 6;

    const int d0 = lane >> 4;         // 0..3
    const int c0 = (lane & 15) << 2;  // 0,4,...,60

    // Hoist W fragments into registers (reused for all rows this wave handles):
    // Wa[j][k] = W[c0+j, k, d0], Wb[j][k] = W[c0+j, k, d0+4]
    float Wa[4][8], Wb[4][8];
#pragma unroll
    for (int j = 0; j < 4; ++j) {
        const float* wp = W + (size_t)(c0 + j) * 64 + d0;
#pragma unroll
        for (int k = 0; k < 8; ++k) {
            Wa[j][k] = wp[k * 8];
            Wb[j][k] = wp[k * 8 + 4];
        }
    }

    const float4* __restrict__ x4   = reinterpret_cast<const float4*>(x);
    float4* __restrict__       out4 = reinterpret_cast<float4*>(out);

    for (int v = wave; v < V; v += nwav) {
        const float4 a = x4[(size_t)v * 128 + lane];
        const float4 b = x4[(size_t)v * 128 + 64 + lane];
        const float xa[4] = {a.x, a.y, a.z, a.w};
        const float xb[4] = {b.x, b.y, b.z, b.w};

        // Stage 1 partials: p[k] = sum_j xa[j]*Wa[j][k] + xb[j]*Wb[j][k]
        float p[8];
#pragma unroll
        for (int k = 0; k < 8; ++k) {
            float acc = 0.0f;
#pragma unroll
            for (int j = 0; j < 4; ++j) {
                acc = fmaf(xa[j], Wa[j][k], acc);
                acc = fmaf(xb[j], Wb[j][k], acc);
            }
            p[k] = acc;
        }

        // Cross-row reduce (xor 16, 32): p[k] = per-column sum across the 4 rows
#pragma unroll
        for (int k = 0; k < 8; ++k) {
            p[k] += __shfl_xor(p[k], 16, 64);
            p[k] += __shfl_xor(p[k], 32, 64);
        }

        // Each 16-lane row only needs s[d0] and s[d0+4]; d0 is row-uniform so a
        // cndmask-select (compile-time reg indices) is valid before the
        // within-row butterfly.
        float u = (d0 & 2) ? ((d0 & 1) ? p[3] : p[2]) : ((d0 & 1) ? p[1] : p[0]);
        float w = (d0 & 2) ? ((d0 & 1) ? p[7] : p[6]) : ((d0 & 1) ? p[5] : p[4]);
#pragma unroll
        for (int m = 1; m <= 8; m <<= 1) {
            u += __shfl_xor(u, m, 64);
            w += __shfl_xor(w, m, 64);
        }
        // Now u = s[d0], w = s[d0+4], replicated across the row's 16 lanes.

        // Stage 2: xOx[v, c0+j] = sum_k s[k]*xr[v,k,c0+j]
        // This lane contributes s[d0]*xa[j] + s[d0+4]*xb[j]; sum across rows.
        float q0 = fmaf(u, xa[0], w * xb[0]);
        float q1 = fmaf(u, xa[1], w * xb[1]);
        float q2 = fmaf(u, xa[2], w * xb[2]);
        float q3 = fmaf(u, xa[3], w * xb[3]);
        q0 += __shfl_xor(q0, 16, 64); q0 += __shfl_xor(q0, 32, 64);
        q1 += __shfl_xor(q1, 16, 64); q1 += __shfl_xor(q1, 32, 64);
        q2 += __shfl_xor(q2, 16, 64); q2 += __shfl_xor(q2, 32, 64);
        q3 += __shfl_xor(q3, 16, 64); q3 += __shfl_xor(q3, 32, 64);

        if (lane < 16) {
            float4 o;
            o.x = fast_tanh(q0);
            o.y = fast_tanh(q1);
            o.z = fast_tanh(q2);
            o.w = fast_tanh(q3);
            out4[(size_t)v * 16 + lane] = o;
        }
    }
}

extern "C" void kernel_launch(void* const* d_in, const int* in_sizes, int n_in,
                              void* d_out, int out_size, void* d_ws, size_t ws_size,
                              hipStream_t stream) {
    const float* x = (const float*)d_in[0];
    const float* W = (const float*)d_in[1];
    float* out = (float*)d_out;
    const int V = in_sizes[0] / 512;  // C*D = 512 floats per row

    const int block = 256;
    const int grid  = 2048;  // 8192 waves, grid-stride over V rows
    ipf_kernel<<<grid, block, 0, stream>>>(x, W, out, V);
}

// Round 3
// 92.218 us; speedup vs baseline: 1.0891x; 1.0891x over previous
//
#include <hip/hip_runtime.h>
#include <hip/hip_bf16.h>

// InnerProductFeatures: V=131072, C=64, D=8
//   xr[v,d,c] = x[v, d*64 + c]
//   s[v,k]    = sum_{d,c} xr[v,d,c] * W[c,k,d]     (W flat: c*64 + k*8 + d)
//   xOx[v,i]  = sum_k s[v,k] * xr[v,k,i]
//   out       = tanh(xOx)   shape (V, 64) fp32
//
// One wave per row. Lane l: d0 = l>>4 (the 16-lane "row"), c0 = (l&15)*4.
//   float4 a = xr[v, d0,   c0..c0+3] = x4[v*128 + l]        (1 KiB wave load)
//   float4 b = xr[v, d0+4, c0..c0+3] = x4[v*128 + 64 + l]   (1 KiB wave load)
//
// Reduction strategy (R2 post-mortem: gfx950 permlane*_swap semantics were
// ambiguous and mis-routed lanes — avoid them entirely):
//   - within-16-lane sums: DPP butterfly (quad_perm xor1/xor2, row_half_mirror,
//     row_mirror) — the canonical GPUOpen idiom, VALU pipe, certain semantics.
//   - cross-row (xor16/xor32): __shfl_xor folds, 9 DS ops/row total
//     (R1 had 32 DS ops/row -> DS pipe co-bottleneck at ~40us/CU).

__device__ __forceinline__ float fast_tanh(float x) {
    float e = __expf(2.0f * x);
    return 1.0f - 2.0f / (e + 1.0f);
}

// fold16(a,b): even 16-rows get a[l]+a[l^16]; odd rows get b[l]+b[l^16].
__device__ __forceinline__ float fold16(float a, float b, int lane) {
    float x   = (lane & 16) ? a : b;     // send the value the partner needs
    float sh  = __shfl_xor(x, 16, 64);
    float own = (lane & 16) ? b : a;
    return own + sh;
}

// fold32(a,b): lanes<32 get a[l]+a[l+32]; lanes>=32 get b[l-32]+b[l].
__device__ __forceinline__ float fold32(float a, float b, int lane) {
    float x   = (lane & 32) ? a : b;
    float sh  = __shfl_xor(x, 32, 64);
    float own = (lane & 32) ? b : a;
    return own + sh;
}

// v + dpp(v): quad_perm 0xB1 = xor1, 0x4E = xor2,
// 0x141 = row_half_mirror (xor4 once quad-uniform),
// 0x140 = row_mirror (xor8 once 8-uniform).
template <int CTRL>
__device__ __forceinline__ float dpp_add(float v) {
    int i = __builtin_bit_cast(int, v);
    int p = __builtin_amdgcn_update_dpp(i, i, CTRL, 0xF, 0xF, false);
    return v + __builtin_bit_cast(float, p);
}

// Full within-16-lane sum (result uniform across the 16 lanes). VALU-only.
__device__ __forceinline__ float row16_sum(float v) {
    v = dpp_add<0xB1>(v);   // xor1
    v = dpp_add<0x4E>(v);   // xor2
    v = dpp_add<0x141>(v);  // xor4 (half mirror)
    v = dpp_add<0x140>(v);  // xor8 (mirror)
    return v;
}

__global__ __launch_bounds__(256, 4)
void ipf_kernel(const float* __restrict__ x, const float* __restrict__ W,
                float* __restrict__ out, int V) {
    const int tid  = blockIdx.x * blockDim.x + threadIdx.x;
    const int lane = threadIdx.x & 63;
    const int wave = tid >> 6;
    const int nwav = (gridDim.x * blockDim.x) >> 6;

    const int d0 = lane >> 4;         // 0..3
    const int c0 = (lane & 15) << 2;  // 0,4,...,60

    // W fragments in registers: Wa[j][k] = W[c0+j, k, d0], Wb = at d0+4.
    float Wa[4][8], Wb[4][8];
#pragma unroll
    for (int j = 0; j < 4; ++j) {
        const float* wp = W + (size_t)(c0 + j) * 64 + d0;
#pragma unroll
        for (int k = 0; k < 8; ++k) {
            Wa[j][k] = wp[k * 8];
            Wb[j][k] = wp[k * 8 + 4];
        }
    }

    const float4* __restrict__ x4 = reinterpret_cast<const float4*>(x);

    int v = wave;
    if (v >= V) return;
    float4 a = x4[(size_t)v * 128 + lane];
    float4 b = x4[(size_t)v * 128 + 64 + lane];

    while (true) {
        const int vn = v + nwav;
        const bool more = (vn < V);
        float4 an = a, bn = b;
        if (more) {  // prefetch next row: 2 KiB in flight during compute
            an = x4[(size_t)vn * 128 + lane];
            bn = x4[(size_t)vn * 128 + 64 + lane];
        }

        const float xa[4] = {a.x, a.y, a.z, a.w};
        const float xb[4] = {b.x, b.y, b.z, b.w};

        // Stage 1 partials: p[k] = sum_j xa[j]*Wa[j][k] + xb[j]*Wb[j][k]
        float p[8];
#pragma unroll
        for (int k = 0; k < 8; ++k) {
            float acc = 0.0f;
#pragma unroll
            for (int j = 0; j < 4; ++j) {
                acc = fmaf(xa[j], Wa[j][k], acc);
                acc = fmaf(xb[j], Wb[j][k], acc);
            }
            p[k] = acc;
        }

        // Within-row sums first (DPP, VALU pipe): R_r[k], row-uniform.
#pragma unroll
        for (int k = 0; k < 8; ++k) p[k] = row16_sum(p[k]);

        // Cross-row folds (6 shfl): route s[d0] -> u, s[d0+4] -> w.
        // t0: even rows hold (R0+R1)[k=0] / (R2+R3)[0]; odd rows k=1. etc.
        float t0 = fold16(p[0], p[1], lane);
        float t1 = fold16(p[2], p[3], lane);
        float t2 = fold16(p[4], p[5], lane);
        float t3 = fold16(p[6], p[7], lane);
        // u: row r gets t-pair sum = s[r]; w: row r gets s[4+r].
        float u = fold32(t0, t1, lane);   // = s[d0]
        float w = fold32(t2, t3, lane);   // = s[d0+4]

        // Stage 2: this lane's contribution to column c0+j from rows d0, d0+4.
        float q0 = fmaf(u, xa[0], w * xb[0]);
        float q1 = fmaf(u, xa[1], w * xb[1]);
        float q2 = fmaf(u, xa[2], w * xb[2]);
        float q3 = fmaf(u, xa[3], w * xb[3]);

        // Reduce q over the 4 rows (3 shfl); result one-column-per-lane:
        // row 0 lanes: q0 full, row 1: q1, row 2: q2, row 3: q3.
        float A = fold16(q0, q1, lane);
        float B = fold16(q2, q3, lane);
        float r = fold32(A, B, lane);

        const int col = ((lane & 15) << 2) + d0;
        out[(size_t)v * 64 + col] = fast_tanh(r);

        if (!more) break;
        v = vn; a = an; b = bn;
    }
}

extern "C" void kernel_launch(void* const* d_in, const int* in_sizes, int n_in,
                              void* d_out, int out_size, void* d_ws, size_t ws_size,
                              hipStream_t stream) {
    const float* x = (const float*)d_in[0];
    const float* W = (const float*)d_in[1];
    float* out = (float*)d_out;
    const int V = in_sizes[0] / 512;  // C*D = 512 floats per row

    const int block = 256;
    const int grid  = 2048;  // 8192 waves, 16 rows each
    ipf_kernel<<<grid, block, 0, stream>>>(x, W, out, V);
}